// Round 7
// baseline (413.698 us; speedup 1.0000x reference)
//
#include <hip/hip_runtime.h>

typedef unsigned short ushort_t;
typedef __attribute__((ext_vector_type(8))) short bf16x8;
typedef __attribute__((ext_vector_type(4))) float f32x4;

// ---------- helpers ----------

__device__ __forceinline__ ushort_t f2bf(float f) {
    union { float f; unsigned u; } c; c.f = f;
    unsigned u = c.u;
    unsigned r = (u + 0x7fffu + ((u >> 16) & 1u)) >> 16;   // round-to-nearest-even
    return (ushort_t)r;
}

// pack two f32 -> one dword of 2x bf16 (no builtin on gfx950; single VOP3)
__device__ __forceinline__ unsigned pk_bf16(float a, float b) {
    unsigned r;
    asm("v_cvt_pk_bf16_f32 %0, %1, %2" : "=v"(r) : "v"(a), "v"(b));
    return r;
}

// async global->LDS, 16B per lane. LDS dest is wave-uniform base; HW writes
// lane i at base + i*16.
__device__ __forceinline__ void gld_lds16(const ushort_t* g, ushort_t* l) {
    __builtin_amdgcn_global_load_lds(
        (const __attribute__((address_space(1))) void*)g,
        (__attribute__((address_space(3))) void*)l, 16, 0, 0);
}

// ---------- fp32 -> bf16 convert (x, w_attn, w_proj fused; block-aligned splits) ----------

__global__ __launch_bounds__(256) void convert_all(
    const float* __restrict__ x, const float* __restrict__ wa, const float* __restrict__ wp,
    ushort_t* __restrict__ xb, ushort_t* __restrict__ wab, ushort_t* __restrict__ wpb)
{
    const int i = blockIdx.x * blockDim.x + threadIdx.x;   // float4 units
    // x: 8192*1024/4 = 2097152 ; wa: 3072*1024/4 = 786432 ; wp: 1024*1024/4 = 262144
    const float* src; ushort_t* dst; int j;
    if (i < 2097152)      { src = x;  dst = xb;  j = i; }
    else if (i < 2883584) { src = wa; dst = wab; j = i - 2097152; }
    else                  { src = wp; dst = wpb; j = i - 2883584; }
    const float4 f = ((const float4*)src)[j];
    ushort4 o;
    o.x = f2bf(f.x); o.y = f2bf(f.y); o.z = f2bf(f.z); o.w = f2bf(f.w);
    ((ushort4*)dst)[j] = o;
}

// ---------- QKV GEMM:  C[8192,3072] = X[8192,1024] @ W[3072,1024]^T ----------
// BK=64: 32KB LDS, 16 K-iterations (half the barrier/vmcnt drains of BK=32).
// 64-col rows span exactly 32 banks -> XOR swizzle (group ^ row&7) mandatory.
// Epilogue: per-wave LDS transpose -> coalesced stores.
// q pre-scaled by 0.125*log2e -> [B,H,S,Dh]; k -> [B,H,S,Dh]; v -> [B,H,Dh,S].

__global__ __launch_bounds__(256) void gemm_qkv(
    const ushort_t* __restrict__ A, const ushort_t* __restrict__ W,
    ushort_t* __restrict__ qo, ushort_t* __restrict__ ko, ushort_t* __restrict__ vto)
{
    constexpr int K = 1024;
    const int m0 = blockIdx.x * 128;
    const int n0 = blockIdx.y * 128;
    __shared__ alignas(16) ushort_t smem[16384];   // sA 16KB | sB 16KB ; epilogue reuse
    ushort_t* sA = smem;
    ushort_t* sB = smem + 8192;
    const int tid = threadIdx.x;
    const int wave = tid >> 6, lane = tid & 63;
    const int quad = lane >> 4, l16 = lane & 15;
    const int l8 = lane & 7;
    const int wm = (wave >> 1) << 6, wn = (wave & 1) << 6;
    const int srow8 = lane >> 3;                    // row within 8-row chunk
    const int sg = ((l8 ^ srow8) << 3);             // swizzled source column-group

    f32x4 acc[4][4] = {};
    // wave stages chunks wave*4+c (A and B): rows chunk*8+srow8, col-group sg
    const ushort_t* aRow0 = A + (size_t)(m0 + wave * 32 + srow8) * K + sg;
    const ushort_t* bRow0 = W + (size_t)(n0 + wave * 32 + srow8) * K + sg;

    for (int k0 = 0; k0 < K; k0 += 64) {
#pragma unroll
        for (int c = 0; c < 4; ++c) {
            gld_lds16(aRow0 + (size_t)c * 8 * K + k0, sA + (wave * 4 + c) * 512);
            gld_lds16(bRow0 + (size_t)c * 8 * K + k0, sB + (wave * 4 + c) * 512);
        }
        __syncthreads();
#pragma unroll
        for (int ks = 0; ks < 2; ++ks) {
            bf16x8 af[4], bfr[4];
#pragma unroll
            for (int f = 0; f < 4; ++f) {
                const int rg = (((ks * 4 + quad) ^ l8) << 3);
                af[f]  = *(const bf16x8*)(sA + (wm + f * 16 + l16) * 64 + rg);
                bfr[f] = *(const bf16x8*)(sB + (wn + f * 16 + l16) * 64 + rg);
            }
#pragma unroll
            for (int mf = 0; mf < 4; ++mf)
#pragma unroll
                for (int nf = 0; nf < 4; ++nf)
                    acc[mf][nf] = __builtin_amdgcn_mfma_f32_16x16x32_bf16(af[mf], bfr[nf], acc[mf][nf], 0, 0, 0);
        }
        __syncthreads();
    }
    // after the loop's final barrier no wave touches sA/sB -> wave-private reuse OK

    const int which = n0 >> 10;                 // block-uniform: 0=q 1=k 2=v
    ushort_t* sT = smem + wave * 2048;          // per-wave 2KB transpose buffer
    const int b  = (m0 + wm) >> 11;
    const int sb = (m0 + wm) & 2047;
    const int h  = ((n0 + wn) & 1023) >> 6;     // wave tile spans exactly one head
    const int bh = b * 16 + h;

    if (which < 2) {
        // q/k: output rows are s (=m), contiguous along dh (=n, 64 wide = 128B)
        ushort_t* go = (which == 0) ? qo : ko;
        const float qs1 = (which == 0) ? 0.18033688011112042f : 1.0f;  // 0.125*log2(e)
#pragma unroll
        for (int mf = 0; mf < 4; ++mf) {
#pragma unroll
            for (int nf = 0; nf < 4; ++nf)
#pragma unroll
                for (int i = 0; i < 4; ++i) {
                    const int mll = quad * 4 + i;
                    sT[mll * 64 + ((nf * 16 + l16) ^ (4 * (mll & 7)))] = f2bf(acc[mf][nf][i] * qs1);
                }
            __builtin_amdgcn_s_waitcnt(0);   // wave-private write->read
#pragma unroll
            for (int p = 0; p < 4; ++p) {
                const int mll = p * 4 + quad;
                const ushort4 val = *(const ushort4*)(sT + mll * 64 + ((l16 * 4) ^ (4 * (mll & 7))));
                const int s = sb + mf * 16 + mll;
                *(ushort4*)(go + ((size_t)bh * 2048 + s) * 64 + l16 * 4) = val;
            }
            __builtin_amdgcn_s_waitcnt(0);   // reads done before next stripe overwrites
        }
    } else {
        // v: output rows are dh (=n), contiguous along s (=m, 64 wide = 128B)
#pragma unroll
        for (int nf = 0; nf < 4; ++nf) {
#pragma unroll
            for (int mf = 0; mf < 4; ++mf) {
                ushort4 w;
                w.x = f2bf(acc[mf][nf][0]);
                w.y = f2bf(acc[mf][nf][1]);
                w.z = f2bf(acc[mf][nf][2]);
                w.w = f2bf(acc[mf][nf][3]);
                *(ushort4*)(sT + l16 * 64 + ((mf * 16 + quad * 4) ^ (4 * (l16 & 7)))) = w;
            }
            __builtin_amdgcn_s_waitcnt(0);
#pragma unroll
            for (int p = 0; p < 4; ++p) {
                const int nll = p * 4 + quad;
                const ushort4 val = *(const ushort4*)(sT + nll * 64 + ((l16 * 4) ^ (4 * (nll & 7))));
                const int dh = nf * 16 + nll;
                *(ushort4*)(vto + ((size_t)bh * 64 + dh) * 2048 + sb + l16 * 4) = val;
            }
            __builtin_amdgcn_s_waitcnt(0);
        }
    }
}

// ---------- flash attention (causal), bf16 MFMA ----------
// ZERO-LDS / ZERO-BARRIER version. All MFMA operand fragments are contiguous
// 16B global loads (verified unswizzle of the R1 LDS layout):
//   bq[ks]     = Q[wrow][ks*32+quad*8..+7]            (R2-proven direct form)
//   ak[ks][kf] = K[kf*16+l16][ks*32+quad*8..+7]
//   vb[ks][nf] = V^T[nf*16+l16][k0+ks*32+quad*8..+7]
// All 4 waves in a block read identical K/V tiles -> L1 serves 3/4 of reads;
// per-bh K+V (512KB) is L2-resident across the 32 q-blocks (common-mistake
// #7: don't LDS-stage what caches fit). Removing LDS+barriers removes the
// ~190cy/iter ds_read pressure and both per-tile drains; waves run fully
// independent. P stays in registers via cvt_pk + permlane (R6).

__global__ __launch_bounds__(256, 4) void attn(
    const ushort_t* __restrict__ qg_, const ushort_t* __restrict__ kg_,
    const ushort_t* __restrict__ vg_, ushort_t* __restrict__ y)
{
    const int bh = blockIdx.x;
    const int b = bh >> 4, h = bh & 15;
    const int tid = threadIdx.x, wave = tid >> 6, lane = tid & 63;
    const int quad = lane >> 4, l16 = lane & 15;

    const int qy = 31 - (int)blockIdx.y;         // longest blocks dispatched first
    const int q0 = qy * 64;
    const int wrow = q0 + wave * 16 + l16;       // this lane's q-row (B side)

    // per-lane fragment base pointers (16B-aligned)
    const ushort_t* kg = kg_ + (size_t)bh * 2048 * 64 + l16 * 64 + quad * 8;
    const ushort_t* vg = vg_ + (size_t)bh * 64 * 2048 + (size_t)l16 * 2048 + quad * 8;

    bf16x8 bq[2];   // [ks] Q B-fragments, loop-invariant, direct from global
#pragma unroll
    for (int ks = 0; ks < 2; ++ks)
        bq[ks] = *(const bf16x8*)(qg_ + ((size_t)bh * 2048 + wrow) * 64 + ks * 32 + quad * 8);

    f32x4 oacc[4] = {};
    f32x4 lpv = {0.f, 0.f, 0.f, 0.f};   // 4 parallel partial row-sums (q-row l16)

    for (int t = 0; t <= qy; ++t) {
        const int k0 = t * 64;

        // K fragments for tile t, direct from global
        bf16x8 ak[2][4];
#pragma unroll
        for (int ks = 0; ks < 2; ++ks)
#pragma unroll
            for (int kf = 0; kf < 4; ++kf)
                ak[ks][kf] = *(const bf16x8*)(kg + (size_t)(k0 + kf * 16) * 64 + ks * 32);

        // S^T = K Q^T : C-layout col = q (l16), row = key (quad*4+i)
        f32x4 sacc[4] = {};
#pragma unroll
        for (int ks = 0; ks < 2; ++ks)
#pragma unroll
            for (int kf = 0; kf < 4; ++kf)
                sacc[kf] = __builtin_amdgcn_mfma_f32_16x16x32_bf16(ak[ks][kf], bq[ks], sacc[kf], 0, 0, 0);

        // softmax numerator: exp2, pack to bf16 pair-dwords X[kf][u]
        // X[kf][u] at lane(q=l16, quad) = keys kf*16 + quad*4 + {2u, 2u+1}
        const bool diag = (t == qy);
        unsigned Xp0[4], Xp1[4];
#pragma unroll
        for (int kf = 0; kf < 4; ++kf) {
            float pv[4];
#pragma unroll
            for (int i = 0; i < 4; ++i) {
                float sv = sacc[kf][i];
                if (diag) {
                    const int cg = k0 + kf * 16 + quad * 4 + i;
                    sv = (cg <= wrow) ? sv : -3.0e38f;
                }
                pv[i] = __builtin_amdgcn_exp2f(sv);
                lpv[i] += pv[i];
            }
            Xp0[kf] = pk_bf16(pv[0], pv[1]);
            Xp1[kf] = pk_bf16(pv[2], pv[3]);
        }

        // in-register P redistribution to PV A-fragment layout (R6-verified):
        //   permlane32_swap: A=[A0,A1,B0,B1], B=[A2,A3,B2,B3]
        //   permlane16_swap: A=[A0,A2,B0,B2] (=pa dword u),
        //                    B=[A1,A3,B1,B3] (=pa dword 2+u)
        bf16x8 pa[2];
#pragma unroll
        for (int ks = 0; ks < 2; ++ks) {
            unsigned a0 = Xp0[2 * ks], b0 = Xp0[2 * ks + 1];
            asm("v_permlane32_swap_b32 %0, %1" : "+v"(a0), "+v"(b0));
            asm("v_permlane16_swap_b32 %0, %1" : "+v"(a0), "+v"(b0));
            unsigned a1 = Xp1[2 * ks], b1 = Xp1[2 * ks + 1];
            asm("v_permlane32_swap_b32 %0, %1" : "+v"(a1), "+v"(b1));
            asm("v_permlane16_swap_b32 %0, %1" : "+v"(a1), "+v"(b1));
            union { unsigned u4[4]; bf16x8 v; } P;
            P.u4[0] = a0; P.u4[1] = a1; P.u4[2] = b0; P.u4[3] = b1;
            pa[ks] = P.v;
        }

        // O += P V : V fragments direct from global
#pragma unroll
        for (int ks = 0; ks < 2; ++ks) {
            bf16x8 vb[4];
#pragma unroll
            for (int nf = 0; nf < 4; ++nf)
                vb[nf] = *(const bf16x8*)(vg + (size_t)nf * 16 * 2048 + k0 + ks * 32);
#pragma unroll
            for (int nf = 0; nf < 4; ++nf)
                oacc[nf] = __builtin_amdgcn_mfma_f32_16x16x32_bf16(pa[ks], vb[nf], oacc[nf], 0, 0, 0);
        }
    }

    // epilogue: reduce row-sums over quads, shuffle to C-layout rows, store
    float rs = (lpv[0] + lpv[1]) + (lpv[2] + lpv[3]);
    rs += __shfl_xor(rs, 16);
    rs += __shfl_xor(rs, 32);
#pragma unroll
    for (int i = 0; i < 4; ++i) {
        const float inv = 1.0f / __shfl(rs, quad * 4 + i);
        const int r = q0 + wave * 16 + quad * 4 + i;
#pragma unroll
        for (int nf = 0; nf < 4; ++nf)
            y[((size_t)b * 2048 + r) * 1024 + h * 64 + nf * 16 + l16] =
                f2bf(oacc[nf][i] * inv);
    }
}

// ---------- proj GEMM: out[8192,1024] = Y[8192,1024] @ Wp[1024,1024]^T (fp32 out) ----------
// BK=64, same structure as gemm_qkv.

__global__ __launch_bounds__(256) void gemm_proj(
    const ushort_t* __restrict__ A, const ushort_t* __restrict__ W, float* __restrict__ out)
{
    constexpr int K = 1024;
    const int m0 = blockIdx.x * 128;
    const int n0 = blockIdx.y * 128;
    __shared__ alignas(16) ushort_t smem[16384];
    ushort_t* sA = smem;
    ushort_t* sB = smem + 8192;
    const int tid = threadIdx.x;
    const int wave = tid >> 6, lane = tid & 63;
    const int quad = lane >> 4, l16 = lane & 15;
    const int l8 = lane & 7;
    const int wm = (wave >> 1) << 6, wn = (wave & 1) << 6;
    const int srow8 = lane >> 3;
    const int sg = ((l8 ^ srow8) << 3);

    f32x4 acc[4][4] = {};
    const ushort_t* aRow0 = A + (size_t)(m0 + wave * 32 + srow8) * K + sg;
    const ushort_t* bRow0 = W + (size_t)(n0 + wave * 32 + srow8) * K + sg;

    for (int k0 = 0; k0 < K; k0 += 64) {
#pragma unroll
        for (int c = 0; c < 4; ++c) {
            gld_lds16(aRow0 + (size_t)c * 8 * K + k0, sA + (wave * 4 + c) * 512);
            gld_lds16(bRow0 + (size_t)c * 8 * K + k0, sB + (wave * 4 + c) * 512);
        }
        __syncthreads();
#pragma unroll
        for (int ks = 0; ks < 2; ++ks) {
            bf16x8 af[4], bfr[4];
#pragma unroll
            for (int f = 0; f < 4; ++f) {
                const int rg = (((ks * 4 + quad) ^ l8) << 3);
                af[f]  = *(const bf16x8*)(sA + (wm + f * 16 + l16) * 64 + rg);
                bfr[f] = *(const bf16x8*)(sB + (wn + f * 16 + l16) * 64 + rg);
            }
#pragma unroll
            for (int mf = 0; mf < 4; ++mf)
#pragma unroll
                for (int nf = 0; nf < 4; ++nf)
                    acc[mf][nf] = __builtin_amdgcn_mfma_f32_16x16x32_bf16(af[mf], bfr[nf], acc[mf][nf], 0, 0, 0);
        }
        __syncthreads();
    }

#pragma unroll
    for (int mf = 0; mf < 4; ++mf)
#pragma unroll
        for (int nf = 0; nf < 4; ++nf)
#pragma unroll
            for (int i = 0; i < 4; ++i) {
                const int m = m0 + wm + mf * 16 + quad * 4 + i;
                const int n = n0 + wn + nf * 16 + l16;
                out[(size_t)m * 1024 + n] = acc[mf][nf][i];
            }
}

// ---------- launch ----------

extern "C" void kernel_launch(void* const* d_in, const int* in_sizes, int n_in,
                              void* d_out, int out_size, void* d_ws, size_t ws_size,
                              hipStream_t stream) {
    const float* x  = (const float*)d_in[0];
    const float* wa = (const float*)d_in[1];
    const float* wp = (const float*)d_in[2];
    float* out = (float*)d_out;

    char* ws = (char*)d_ws;
    // layout (bytes): xb 16MiB | wab 6MiB | wpb 2MiB | q 16MiB | k 16MiB | vt 16MiB
    ushort_t* xb  = (ushort_t*)(ws);
    ushort_t* wab = (ushort_t*)(ws + 16777216);
    ushort_t* wpb = (ushort_t*)(ws + 16777216 + 6291456);
    ushort_t* q   = (ushort_t*)(ws + 25165824);
    ushort_t* k   = (ushort_t*)(ws + 41943040);
    ushort_t* vt  = (ushort_t*)(ws + 58720256);
    ushort_t* y   = xb;   // xb dead after gemm_qkv; reuse for attention output

    convert_all<<<12288, 256, 0, stream>>>(x, wa, wp, xb, wab, wpb);

    gemm_qkv<<<dim3(64, 24), 256, 0, stream>>>(xb, wab, q, k, vt);
    attn<<<dim3(64, 32), 256, 0, stream>>>(q, k, vt, y);
    gemm_proj<<<dim3(64, 8), 256, 0, stream>>>(y, wpb, out);
}

// Round 8
// 224.961 us; speedup vs baseline: 1.8390x; 1.8390x over previous
//
#include <hip/hip_runtime.h>

typedef unsigned short ushort_t;
typedef __attribute__((ext_vector_type(8))) short bf16x8;
typedef __attribute__((ext_vector_type(4))) float f32x4;

// ---------- helpers ----------

__device__ __forceinline__ ushort_t f2bf(float f) {
    union { float f; unsigned u; } c; c.f = f;
    unsigned u = c.u;
    unsigned r = (u + 0x7fffu + ((u >> 16) & 1u)) >> 16;   // round-to-nearest-even
    return (ushort_t)r;
}

// pack two f32 -> one dword of 2x bf16 (no builtin on gfx950; single VOP3)
__device__ __forceinline__ unsigned pk_bf16(float a, float b) {
    unsigned r;
    asm("v_cvt_pk_bf16_f32 %0, %1, %2" : "=v"(r) : "v"(a), "v"(b));
    return r;
}

// async global->LDS, 16B per lane. LDS dest is wave-uniform base; HW writes
// lane i at base + i*16.
__device__ __forceinline__ void gld_lds16(const ushort_t* g, ushort_t* l) {
    __builtin_amdgcn_global_load_lds(
        (const __attribute__((address_space(1))) void*)g,
        (__attribute__((address_space(3))) void*)l, 16, 0, 0);
}

// ---------- fp32 -> bf16 convert (x, w_attn, w_proj fused; block-aligned splits) ----------

__global__ __launch_bounds__(256) void convert_all(
    const float* __restrict__ x, const float* __restrict__ wa, const float* __restrict__ wp,
    ushort_t* __restrict__ xb, ushort_t* __restrict__ wab, ushort_t* __restrict__ wpb)
{
    const int i = blockIdx.x * blockDim.x + threadIdx.x;   // float4 units
    // x: 8192*1024/4 = 2097152 ; wa: 3072*1024/4 = 786432 ; wp: 1024*1024/4 = 262144
    const float* src; ushort_t* dst; int j;
    if (i < 2097152)      { src = x;  dst = xb;  j = i; }
    else if (i < 2883584) { src = wa; dst = wab; j = i - 2097152; }
    else                  { src = wp; dst = wpb; j = i - 2883584; }
    const float4 f = ((const float4*)src)[j];
    ushort4 o;
    o.x = f2bf(f.x); o.y = f2bf(f.y); o.z = f2bf(f.z); o.w = f2bf(f.w);
    ((ushort4*)dst)[j] = o;
}

// ---------- QKV GEMM:  C[8192,3072] = X[8192,1024] @ W[3072,1024]^T ----------
// BK=64: 32KB LDS, 16 K-iterations (half the barrier/vmcnt drains of BK=32).
// 64-col rows span exactly 32 banks -> XOR swizzle (group ^ row&7) mandatory.
// Epilogue: per-wave LDS transpose -> coalesced stores.
// q pre-scaled by 0.125*log2e -> [B,H,S,Dh]; k -> [B,H,S,Dh]; v -> [B,H,Dh,S].

__global__ __launch_bounds__(256) void gemm_qkv(
    const ushort_t* __restrict__ A, const ushort_t* __restrict__ W,
    ushort_t* __restrict__ qo, ushort_t* __restrict__ ko, ushort_t* __restrict__ vto)
{
    constexpr int K = 1024;
    const int m0 = blockIdx.x * 128;
    const int n0 = blockIdx.y * 128;
    __shared__ alignas(16) ushort_t smem[16384];   // sA 16KB | sB 16KB ; epilogue reuse
    ushort_t* sA = smem;
    ushort_t* sB = smem + 8192;
    const int tid = threadIdx.x;
    const int wave = tid >> 6, lane = tid & 63;
    const int quad = lane >> 4, l16 = lane & 15;
    const int l8 = lane & 7;
    const int wm = (wave >> 1) << 6, wn = (wave & 1) << 6;
    const int srow8 = lane >> 3;                    // row within 8-row chunk
    const int sg = ((l8 ^ srow8) << 3);             // swizzled source column-group

    f32x4 acc[4][4] = {};
    // wave stages chunks wave*4+c (A and B): rows chunk*8+srow8, col-group sg
    const ushort_t* aRow0 = A + (size_t)(m0 + wave * 32 + srow8) * K + sg;
    const ushort_t* bRow0 = W + (size_t)(n0 + wave * 32 + srow8) * K + sg;

    for (int k0 = 0; k0 < K; k0 += 64) {
#pragma unroll
        for (int c = 0; c < 4; ++c) {
            gld_lds16(aRow0 + (size_t)c * 8 * K + k0, sA + (wave * 4 + c) * 512);
            gld_lds16(bRow0 + (size_t)c * 8 * K + k0, sB + (wave * 4 + c) * 512);
        }
        __syncthreads();
#pragma unroll
        for (int ks = 0; ks < 2; ++ks) {
            bf16x8 af[4], bfr[4];
#pragma unroll
            for (int f = 0; f < 4; ++f) {
                const int rg = (((ks * 4 + quad) ^ l8) << 3);
                af[f]  = *(const bf16x8*)(sA + (wm + f * 16 + l16) * 64 + rg);
                bfr[f] = *(const bf16x8*)(sB + (wn + f * 16 + l16) * 64 + rg);
            }
#pragma unroll
            for (int mf = 0; mf < 4; ++mf)
#pragma unroll
                for (int nf = 0; nf < 4; ++nf)
                    acc[mf][nf] = __builtin_amdgcn_mfma_f32_16x16x32_bf16(af[mf], bfr[nf], acc[mf][nf], 0, 0, 0);
        }
        __syncthreads();
    }
    // after the loop's final barrier no wave touches sA/sB -> wave-private reuse OK

    const int which = n0 >> 10;                 // block-uniform: 0=q 1=k 2=v
    ushort_t* sT = smem + wave * 2048;          // per-wave 2KB transpose buffer
    const int b  = (m0 + wm) >> 11;
    const int sb = (m0 + wm) & 2047;
    const int h  = ((n0 + wn) & 1023) >> 6;     // wave tile spans exactly one head
    const int bh = b * 16 + h;

    if (which < 2) {
        // q/k: output rows are s (=m), contiguous along dh (=n, 64 wide = 128B)
        ushort_t* go = (which == 0) ? qo : ko;
        const float qs1 = (which == 0) ? 0.18033688011112042f : 1.0f;  // 0.125*log2(e)
#pragma unroll
        for (int mf = 0; mf < 4; ++mf) {
#pragma unroll
            for (int nf = 0; nf < 4; ++nf)
#pragma unroll
                for (int i = 0; i < 4; ++i) {
                    const int mll = quad * 4 + i;
                    sT[mll * 64 + ((nf * 16 + l16) ^ (4 * (mll & 7)))] = f2bf(acc[mf][nf][i] * qs1);
                }
            __builtin_amdgcn_s_waitcnt(0);   // wave-private write->read
#pragma unroll
            for (int p = 0; p < 4; ++p) {
                const int mll = p * 4 + quad;
                const ushort4 val = *(const ushort4*)(sT + mll * 64 + ((l16 * 4) ^ (4 * (mll & 7))));
                const int s = sb + mf * 16 + mll;
                *(ushort4*)(go + ((size_t)bh * 2048 + s) * 64 + l16 * 4) = val;
            }
            __builtin_amdgcn_s_waitcnt(0);   // reads done before next stripe overwrites
        }
    } else {
        // v: output rows are dh (=n), contiguous along s (=m, 64 wide = 128B)
#pragma unroll
        for (int nf = 0; nf < 4; ++nf) {
#pragma unroll
            for (int mf = 0; mf < 4; ++mf) {
                ushort4 w;
                w.x = f2bf(acc[mf][nf][0]);
                w.y = f2bf(acc[mf][nf][1]);
                w.z = f2bf(acc[mf][nf][2]);
                w.w = f2bf(acc[mf][nf][3]);
                *(ushort4*)(sT + l16 * 64 + ((mf * 16 + quad * 4) ^ (4 * (l16 & 7)))) = w;
            }
            __builtin_amdgcn_s_waitcnt(0);
#pragma unroll
            for (int p = 0; p < 4; ++p) {
                const int nll = p * 4 + quad;
                const ushort4 val = *(const ushort4*)(sT + nll * 64 + ((l16 * 4) ^ (4 * (nll & 7))));
                const int dh = nf * 16 + nll;
                *(ushort4*)(vto + ((size_t)bh * 64 + dh) * 2048 + sb + l16 * 4) = val;
            }
            __builtin_amdgcn_s_waitcnt(0);
        }
    }
}

// ---------- flash attention (causal), bf16 MFMA ----------
// 8-wave (512-thread) blocks, 128-row q-tile, 16 q-rows/wave: per-wave
// compute code is byte-identical to the R6 version (LDS K/V + in-register
// P via cvt_pk+permlane); what changes is amortization:
//  - K/V tile staged by 8 waves -> 2 gld_lds16/wave/tile (was 4)
//  - block count halves -> barrier events per unit work halve
//  - 4 blocks x 8 waves = 32 waves/CU (thread-limited 100% occupancy;
//    LDS 32KB x 4 = 128KB <= 160KB), vs 36% measured at R6.
// Causal guards per R2's proven pattern: barriers unconditional, compute
// guarded by block-uniform-per-wave act; loop bound 2qt+2 block-uniform.

__global__ __launch_bounds__(512) void attn(
    const ushort_t* __restrict__ qg_, const ushort_t* __restrict__ kg_,
    const ushort_t* __restrict__ vg_, ushort_t* __restrict__ y)
{
    const int bh = blockIdx.x;
    const int b = bh >> 4, h = bh & 15;
    const int tid = threadIdx.x, wave = tid >> 6, lane = tid & 63;
    const int quad = lane >> 4, l16 = lane & 15;
    const int l8 = lane & 7;

    __shared__ alignas(16) ushort_t sQ[8192];   // 16KB: 128 q-rows x 64 (per-wave 16-row regions)
    __shared__ alignas(16) ushort_t sK[4096];   // 8KB: 64 keys x 64
    __shared__ alignas(16) ushort_t sV[4096];   // 8KB: [dh][s_local]

    const ushort_t* kg = kg_ + (size_t)bh * 2048 * 64;
    const ushort_t* vg = vg_ + (size_t)bh * 64 * 2048;

    const int srow8 = lane >> 3;
    const int sg = ((l8 ^ srow8) << 3);          // swizzled staging column-group

    const int qt = 15 - (int)blockIdx.y;         // longest blocks dispatched first
    const int q0 = qt * 128;
    const int wbase = q0 + wave * 16;            // this wave's first q-row
    const int wrow = wbase + l16;                // this lane's q-row (B side)

    {   // stage this wave's 16 Q rows (swizzled, wave-private region)
        const ushort_t* qg = qg_ + ((size_t)bh * 2048 + wbase) * 64;
#pragma unroll
        for (int c = 0; c < 2; ++c)
            gld_lds16(qg + (size_t)(c * 8 + srow8) * 64 + sg, sQ + (wave * 2 + c) * 512);
    }
    __builtin_amdgcn_s_waitcnt(0);   // own-wave staging -> own-wave frag read

    bf16x8 bq[2];   // [ks] Q B-fragments for rows wbase+l16, loop-invariant
#pragma unroll
    for (int ks = 0; ks < 2; ++ks)
        bq[ks] = *(const bf16x8*)(sQ + (wave * 16 + l16) * 64 + (((ks * 4 + quad) ^ l8) << 3));

    f32x4 oacc[4] = {};
    f32x4 lpv = {0.f, 0.f, 0.f, 0.f};   // 4 parallel partial row-sums (q-row l16)

    const int tmax = 2 * qt + 1;
    for (int t = 0; t <= tmax; ++t) {
        const int k0 = t * 64;
        __syncthreads();   // prior iter's sK/sV readers done before restaging
        // 8 waves cooperatively stage the 64-key K and V tiles: 1 chunk each
        gld_lds16(kg + (size_t)(k0 + wave * 8 + srow8) * 64 + sg, sK + wave * 512);
        gld_lds16(vg + (size_t)(wave * 8 + srow8) * 2048 + k0 + sg, sV + wave * 512);
        __syncthreads();

        const bool act = (k0 <= wbase + 15);     // any unmasked key for this wave?
        if (act) {
            // S^T = K Q^T : C-layout col = q (l16), row = key (quad*4+i)
            f32x4 sacc[4] = {};
#pragma unroll
            for (int ks = 0; ks < 2; ++ks) {
                bf16x8 ak[4];
#pragma unroll
                for (int kf = 0; kf < 4; ++kf)
                    ak[kf] = *(const bf16x8*)(sK + (kf * 16 + l16) * 64 + (((ks * 4 + quad) ^ l8) << 3));
#pragma unroll
                for (int kf = 0; kf < 4; ++kf)
                    sacc[kf] = __builtin_amdgcn_mfma_f32_16x16x32_bf16(ak[kf], bq[ks], sacc[kf], 0, 0, 0);
            }

            // softmax numerator: exp2, pack to bf16 pair-dwords X[kf][u]
            // X[kf][u] at lane(q=l16, quad) = keys kf*16 + quad*4 + {2u, 2u+1}
            const bool msk = (k0 + 63 > wbase);  // tile overlaps the diagonal
            unsigned Xp0[4], Xp1[4];
#pragma unroll
            for (int kf = 0; kf < 4; ++kf) {
                float pv[4];
#pragma unroll
                for (int i = 0; i < 4; ++i) {
                    float sv = sacc[kf][i];
                    if (msk) {
                        const int cg = k0 + kf * 16 + quad * 4 + i;
                        sv = (cg <= wrow) ? sv : -3.0e38f;
                    }
                    pv[i] = __builtin_amdgcn_exp2f(sv);
                    lpv[i] += pv[i];
                }
                Xp0[kf] = pk_bf16(pv[0], pv[1]);
                Xp1[kf] = pk_bf16(pv[2], pv[3]);
            }

            // in-register P redistribution to PV A-fragment layout (R6-verified):
            //   permlane32_swap: A=[A0,A1,B0,B1], B=[A2,A3,B2,B3]
            //   permlane16_swap: A=[A0,A2,B0,B2] (=pa dword u),
            //                    B=[A1,A3,B1,B3] (=pa dword 2+u)
            bf16x8 pa[2];
#pragma unroll
            for (int ks = 0; ks < 2; ++ks) {
                unsigned a0 = Xp0[2 * ks], b0 = Xp0[2 * ks + 1];
                asm("v_permlane32_swap_b32 %0, %1" : "+v"(a0), "+v"(b0));
                asm("v_permlane16_swap_b32 %0, %1" : "+v"(a0), "+v"(b0));
                unsigned a1 = Xp1[2 * ks], b1 = Xp1[2 * ks + 1];
                asm("v_permlane32_swap_b32 %0, %1" : "+v"(a1), "+v"(b1));
                asm("v_permlane16_swap_b32 %0, %1" : "+v"(a1), "+v"(b1));
                union { unsigned u4[4]; bf16x8 v; } P;
                P.u4[0] = a0; P.u4[1] = a1; P.u4[2] = b0; P.u4[3] = b1;
                pa[ks] = P.v;
            }

            // O += P V (pa from registers; vb from swizzled sV)
#pragma unroll
            for (int ks = 0; ks < 2; ++ks) {
                const int rgrp = (((ks * 4 + quad) ^ l8) << 3);
                bf16x8 vb[4];
#pragma unroll
                for (int nf = 0; nf < 4; ++nf)
                    vb[nf] = *(const bf16x8*)(sV + (nf * 16 + l16) * 64 + rgrp);
#pragma unroll
                for (int nf = 0; nf < 4; ++nf)
                    oacc[nf] = __builtin_amdgcn_mfma_f32_16x16x32_bf16(pa[ks], vb[nf], oacc[nf], 0, 0, 0);
            }
        }
    }

    // epilogue: reduce row-sums over quads, shuffle to C-layout rows, store
    float rs = (lpv[0] + lpv[1]) + (lpv[2] + lpv[3]);
    rs += __shfl_xor(rs, 16);
    rs += __shfl_xor(rs, 32);
#pragma unroll
    for (int i = 0; i < 4; ++i) {
        const float inv = 1.0f / __shfl(rs, quad * 4 + i);
        const int r = wbase + quad * 4 + i;
#pragma unroll
        for (int nf = 0; nf < 4; ++nf)
            y[((size_t)b * 2048 + r) * 1024 + h * 64 + nf * 16 + l16] =
                f2bf(oacc[nf][i] * inv);
    }
}

// ---------- proj GEMM: out[8192,1024] = Y[8192,1024] @ Wp[1024,1024]^T (fp32 out) ----------
// BK=64, same structure as gemm_qkv.

__global__ __launch_bounds__(256) void gemm_proj(
    const ushort_t* __restrict__ A, const ushort_t* __restrict__ W, float* __restrict__ out)
{
    constexpr int K = 1024;
    const int m0 = blockIdx.x * 128;
    const int n0 = blockIdx.y * 128;
    __shared__ alignas(16) ushort_t smem[16384];
    ushort_t* sA = smem;
    ushort_t* sB = smem + 8192;
    const int tid = threadIdx.x;
    const int wave = tid >> 6, lane = tid & 63;
    const int quad = lane >> 4, l16 = lane & 15;
    const int l8 = lane & 7;
    const int wm = (wave >> 1) << 6, wn = (wave & 1) << 6;
    const int srow8 = lane >> 3;
    const int sg = ((l8 ^ srow8) << 3);

    f32x4 acc[4][4] = {};
    const ushort_t* aRow0 = A + (size_t)(m0 + wave * 32 + srow8) * K + sg;
    const ushort_t* bRow0 = W + (size_t)(n0 + wave * 32 + srow8) * K + sg;

    for (int k0 = 0; k0 < K; k0 += 64) {
#pragma unroll
        for (int c = 0; c < 4; ++c) {
            gld_lds16(aRow0 + (size_t)c * 8 * K + k0, sA + (wave * 4 + c) * 512);
            gld_lds16(bRow0 + (size_t)c * 8 * K + k0, sB + (wave * 4 + c) * 512);
        }
        __syncthreads();
#pragma unroll
        for (int ks = 0; ks < 2; ++ks) {
            bf16x8 af[4], bfr[4];
#pragma unroll
            for (int f = 0; f < 4; ++f) {
                const int rg = (((ks * 4 + quad) ^ l8) << 3);
                af[f]  = *(const bf16x8*)(sA + (wm + f * 16 + l16) * 64 + rg);
                bfr[f] = *(const bf16x8*)(sB + (wn + f * 16 + l16) * 64 + rg);
            }
#pragma unroll
            for (int mf = 0; mf < 4; ++mf)
#pragma unroll
                for (int nf = 0; nf < 4; ++nf)
                    acc[mf][nf] = __builtin_amdgcn_mfma_f32_16x16x32_bf16(af[mf], bfr[nf], acc[mf][nf], 0, 0, 0);
        }
        __syncthreads();
    }

#pragma unroll
    for (int mf = 0; mf < 4; ++mf)
#pragma unroll
        for (int nf = 0; nf < 4; ++nf)
#pragma unroll
            for (int i = 0; i < 4; ++i) {
                const int m = m0 + wm + mf * 16 + quad * 4 + i;
                const int n = n0 + wn + nf * 16 + l16;
                out[(size_t)m * 1024 + n] = acc[mf][nf][i];
            }
}

// ---------- launch ----------

extern "C" void kernel_launch(void* const* d_in, const int* in_sizes, int n_in,
                              void* d_out, int out_size, void* d_ws, size_t ws_size,
                              hipStream_t stream) {
    const float* x  = (const float*)d_in[0];
    const float* wa = (const float*)d_in[1];
    const float* wp = (const float*)d_in[2];
    float* out = (float*)d_out;

    char* ws = (char*)d_ws;
    // layout (bytes): xb 16MiB | wab 6MiB | wpb 2MiB | q 16MiB | k 16MiB | vt 16MiB
    ushort_t* xb  = (ushort_t*)(ws);
    ushort_t* wab = (ushort_t*)(ws + 16777216);
    ushort_t* wpb = (ushort_t*)(ws + 16777216 + 6291456);
    ushort_t* q   = (ushort_t*)(ws + 25165824);
    ushort_t* k   = (ushort_t*)(ws + 41943040);
    ushort_t* vt  = (ushort_t*)(ws + 58720256);
    ushort_t* y   = xb;   // xb dead after gemm_qkv; reuse for attention output

    convert_all<<<12288, 256, 0, stream>>>(x, wa, wp, xb, wab, wpb);

    gemm_qkv<<<dim3(64, 24), 256, 0, stream>>>(xb, wab, q, k, vt);
    attn<<<dim3(64, 16), 512, 0, stream>>>(q, k, vt, y);
    gemm_proj<<<dim3(64, 8), 256, 0, stream>>>(y, wpb, out);
}

// Round 9
// 220.234 us; speedup vs baseline: 1.8784x; 1.0215x over previous
//
#include <hip/hip_runtime.h>

typedef unsigned short ushort_t;
typedef __attribute__((ext_vector_type(8))) short bf16x8;
typedef __attribute__((ext_vector_type(4))) float f32x4;

// ---------- helpers ----------

__device__ __forceinline__ ushort_t f2bf(float f) {
    union { float f; unsigned u; } c; c.f = f;
    unsigned u = c.u;
    unsigned r = (u + 0x7fffu + ((u >> 16) & 1u)) >> 16;   // round-to-nearest-even
    return (ushort_t)r;
}

// pack two f32 -> one dword of 2x bf16 (no builtin on gfx950; single VOP3)
__device__ __forceinline__ unsigned pk_bf16(float a, float b) {
    unsigned r;
    asm("v_cvt_pk_bf16_f32 %0, %1, %2" : "=v"(r) : "v"(a), "v"(b));
    return r;
}

// async global->LDS, 16B per lane. LDS dest is wave-uniform base; HW writes
// lane i at base + i*16.
__device__ __forceinline__ void gld_lds16(const ushort_t* g, ushort_t* l) {
    __builtin_amdgcn_global_load_lds(
        (const __attribute__((address_space(1))) void*)g,
        (__attribute__((address_space(3))) void*)l, 16, 0, 0);
}

// ---------- fp32 -> bf16 convert (x, w_attn, w_proj fused; block-aligned splits) ----------

__global__ __launch_bounds__(256) void convert_all(
    const float* __restrict__ x, const float* __restrict__ wa, const float* __restrict__ wp,
    ushort_t* __restrict__ xb, ushort_t* __restrict__ wab, ushort_t* __restrict__ wpb)
{
    const int i = blockIdx.x * blockDim.x + threadIdx.x;   // float4 units
    // x: 8192*1024/4 = 2097152 ; wa: 3072*1024/4 = 786432 ; wp: 1024*1024/4 = 262144
    const float* src; ushort_t* dst; int j;
    if (i < 2097152)      { src = x;  dst = xb;  j = i; }
    else if (i < 2883584) { src = wa; dst = wab; j = i - 2097152; }
    else                  { src = wp; dst = wpb; j = i - 2883584; }
    const float4 f = ((const float4*)src)[j];
    ushort4 o;
    o.x = f2bf(f.x); o.y = f2bf(f.y); o.z = f2bf(f.z); o.w = f2bf(f.w);
    ((ushort4*)dst)[j] = o;
}

// ---------- QKV GEMM:  C[8192,3072] = X[8192,1024] @ W[3072,1024]^T ----------
// BK=64, XOR-swizzled LDS, per-wave transpose epilogue (unchanged).
// R9: register diet. acc 4x4 f32x4 = 64 AGPR + 128 VGPR ~ 192/wave was
// capping residency at 2 waves/SIMD (Occupancy 19.8%, exposed barrier
// drains, MfmaUtil 32%). __launch_bounds__(256,3) caps allocation at
// ~170 for 3 waves/SIMD; ks-outer loop with single live af frag cuts
// frag liveness 32->20 VGPR to help the allocator fit without hot spills.

__global__ __launch_bounds__(256, 3) void gemm_qkv(
    const ushort_t* __restrict__ A, const ushort_t* __restrict__ W,
    ushort_t* __restrict__ qo, ushort_t* __restrict__ ko, ushort_t* __restrict__ vto)
{
    constexpr int K = 1024;
    const int m0 = blockIdx.x * 128;
    const int n0 = blockIdx.y * 128;
    __shared__ alignas(16) ushort_t smem[16384];   // sA 16KB | sB 16KB ; epilogue reuse
    ushort_t* sA = smem;
    ushort_t* sB = smem + 8192;
    const int tid = threadIdx.x;
    const int wave = tid >> 6, lane = tid & 63;
    const int quad = lane >> 4, l16 = lane & 15;
    const int l8 = lane & 7;
    const int wm = (wave >> 1) << 6, wn = (wave & 1) << 6;
    const int srow8 = lane >> 3;                    // row within 8-row chunk
    const int sg = ((l8 ^ srow8) << 3);             // swizzled source column-group

    f32x4 acc[4][4] = {};
    // wave stages chunks wave*4+c (A and B): rows chunk*8+srow8, col-group sg
    const ushort_t* aRow0 = A + (size_t)(m0 + wave * 32 + srow8) * K + sg;
    const ushort_t* bRow0 = W + (size_t)(n0 + wave * 32 + srow8) * K + sg;

    for (int k0 = 0; k0 < K; k0 += 64) {
#pragma unroll
        for (int c = 0; c < 4; ++c) {
            gld_lds16(aRow0 + (size_t)c * 8 * K + k0, sA + (wave * 4 + c) * 512);
            gld_lds16(bRow0 + (size_t)c * 8 * K + k0, sB + (wave * 4 + c) * 512);
        }
        __syncthreads();
#pragma unroll
        for (int ks = 0; ks < 2; ++ks) {
            const int rg = (((ks * 4 + quad) ^ l8) << 3);
            bf16x8 bfr[4];
#pragma unroll
            for (int nf = 0; nf < 4; ++nf)
                bfr[nf] = *(const bf16x8*)(sB + (wn + nf * 16 + l16) * 64 + rg);
#pragma unroll
            for (int mf = 0; mf < 4; ++mf) {
                const bf16x8 af = *(const bf16x8*)(sA + (wm + mf * 16 + l16) * 64 + rg);
#pragma unroll
                for (int nf = 0; nf < 4; ++nf)
                    acc[mf][nf] = __builtin_amdgcn_mfma_f32_16x16x32_bf16(af, bfr[nf], acc[mf][nf], 0, 0, 0);
            }
        }
        __syncthreads();
    }
    // after the loop's final barrier no wave touches sA/sB -> wave-private reuse OK

    const int which = n0 >> 10;                 // block-uniform: 0=q 1=k 2=v
    ushort_t* sT = smem + wave * 2048;          // per-wave 2KB transpose buffer
    const int b  = (m0 + wm) >> 11;
    const int sb = (m0 + wm) & 2047;
    const int h  = ((n0 + wn) & 1023) >> 6;     // wave tile spans exactly one head
    const int bh = b * 16 + h;

    if (which < 2) {
        // q/k: output rows are s (=m), contiguous along dh (=n, 64 wide = 128B)
        ushort_t* go = (which == 0) ? qo : ko;
        const float qs1 = (which == 0) ? 0.18033688011112042f : 1.0f;  // 0.125*log2(e)
#pragma unroll
        for (int mf = 0; mf < 4; ++mf) {
#pragma unroll
            for (int nf = 0; nf < 4; ++nf)
#pragma unroll
                for (int i = 0; i < 4; ++i) {
                    const int mll = quad * 4 + i;
                    sT[mll * 64 + ((nf * 16 + l16) ^ (4 * (mll & 7)))] = f2bf(acc[mf][nf][i] * qs1);
                }
            __builtin_amdgcn_s_waitcnt(0);   // wave-private write->read
#pragma unroll
            for (int p = 0; p < 4; ++p) {
                const int mll = p * 4 + quad;
                const ushort4 val = *(const ushort4*)(sT + mll * 64 + ((l16 * 4) ^ (4 * (mll & 7))));
                const int s = sb + mf * 16 + mll;
                *(ushort4*)(go + ((size_t)bh * 2048 + s) * 64 + l16 * 4) = val;
            }
            __builtin_amdgcn_s_waitcnt(0);   // reads done before next stripe overwrites
        }
    } else {
        // v: output rows are dh (=n), contiguous along s (=m, 64 wide = 128B)
#pragma unroll
        for (int nf = 0; nf < 4; ++nf) {
#pragma unroll
            for (int mf = 0; mf < 4; ++mf) {
                ushort4 w;
                w.x = f2bf(acc[mf][nf][0]);
                w.y = f2bf(acc[mf][nf][1]);
                w.z = f2bf(acc[mf][nf][2]);
                w.w = f2bf(acc[mf][nf][3]);
                *(ushort4*)(sT + l16 * 64 + ((mf * 16 + quad * 4) ^ (4 * (l16 & 7)))) = w;
            }
            __builtin_amdgcn_s_waitcnt(0);
#pragma unroll
            for (int p = 0; p < 4; ++p) {
                const int nll = p * 4 + quad;
                const ushort4 val = *(const ushort4*)(sT + nll * 64 + ((l16 * 4) ^ (4 * (nll & 7))));
                const int dh = nf * 16 + nll;
                *(ushort4*)(vto + ((size_t)bh * 64 + dh) * 2048 + sb + l16 * 4) = val;
            }
            __builtin_amdgcn_s_waitcnt(0);
        }
    }
}

// ---------- flash attention (causal), bf16 MFMA ----------
// 8-wave (512-thread) blocks, 128-row q-tile, 16 q-rows/wave; K/V in LDS,
// in-register P via cvt_pk + permlane (R6-verified). Unchanged from R8.

__global__ __launch_bounds__(512) void attn(
    const ushort_t* __restrict__ qg_, const ushort_t* __restrict__ kg_,
    const ushort_t* __restrict__ vg_, ushort_t* __restrict__ y)
{
    const int bh = blockIdx.x;
    const int b = bh >> 4, h = bh & 15;
    const int tid = threadIdx.x, wave = tid >> 6, lane = tid & 63;
    const int quad = lane >> 4, l16 = lane & 15;
    const int l8 = lane & 7;

    __shared__ alignas(16) ushort_t sQ[8192];   // 16KB: 128 q-rows x 64 (per-wave 16-row regions)
    __shared__ alignas(16) ushort_t sK[4096];   // 8KB: 64 keys x 64
    __shared__ alignas(16) ushort_t sV[4096];   // 8KB: [dh][s_local]

    const ushort_t* kg = kg_ + (size_t)bh * 2048 * 64;
    const ushort_t* vg = vg_ + (size_t)bh * 64 * 2048;

    const int srow8 = lane >> 3;
    const int sg = ((l8 ^ srow8) << 3);          // swizzled staging column-group

    const int qt = 15 - (int)blockIdx.y;         // longest blocks dispatched first
    const int q0 = qt * 128;
    const int wbase = q0 + wave * 16;            // this wave's first q-row
    const int wrow = wbase + l16;                // this lane's q-row (B side)

    {   // stage this wave's 16 Q rows (swizzled, wave-private region)
        const ushort_t* qg = qg_ + ((size_t)bh * 2048 + wbase) * 64;
#pragma unroll
        for (int c = 0; c < 2; ++c)
            gld_lds16(qg + (size_t)(c * 8 + srow8) * 64 + sg, sQ + (wave * 2 + c) * 512);
    }
    __builtin_amdgcn_s_waitcnt(0);   // own-wave staging -> own-wave frag read

    bf16x8 bq[2];   // [ks] Q B-fragments for rows wbase+l16, loop-invariant
#pragma unroll
    for (int ks = 0; ks < 2; ++ks)
        bq[ks] = *(const bf16x8*)(sQ + (wave * 16 + l16) * 64 + (((ks * 4 + quad) ^ l8) << 3));

    f32x4 oacc[4] = {};
    f32x4 lpv = {0.f, 0.f, 0.f, 0.f};   // 4 parallel partial row-sums (q-row l16)

    const int tmax = 2 * qt + 1;
    for (int t = 0; t <= tmax; ++t) {
        const int k0 = t * 64;
        __syncthreads();   // prior iter's sK/sV readers done before restaging
        // 8 waves cooperatively stage the 64-key K and V tiles: 1 chunk each
        gld_lds16(kg + (size_t)(k0 + wave * 8 + srow8) * 64 + sg, sK + wave * 512);
        gld_lds16(vg + (size_t)(wave * 8 + srow8) * 2048 + k0 + sg, sV + wave * 512);
        __syncthreads();

        const bool act = (k0 <= wbase + 15);     // any unmasked key for this wave?
        if (act) {
            // S^T = K Q^T : C-layout col = q (l16), row = key (quad*4+i)
            f32x4 sacc[4] = {};
#pragma unroll
            for (int ks = 0; ks < 2; ++ks) {
                bf16x8 ak[4];
#pragma unroll
                for (int kf = 0; kf < 4; ++kf)
                    ak[kf] = *(const bf16x8*)(sK + (kf * 16 + l16) * 64 + (((ks * 4 + quad) ^ l8) << 3));
#pragma unroll
                for (int kf = 0; kf < 4; ++kf)
                    sacc[kf] = __builtin_amdgcn_mfma_f32_16x16x32_bf16(ak[kf], bq[ks], sacc[kf], 0, 0, 0);
            }

            // softmax numerator: exp2, pack to bf16 pair-dwords X[kf][u]
            // X[kf][u] at lane(q=l16, quad) = keys kf*16 + quad*4 + {2u, 2u+1}
            const bool msk = (k0 + 63 > wbase);  // tile overlaps the diagonal
            unsigned Xp0[4], Xp1[4];
#pragma unroll
            for (int kf = 0; kf < 4; ++kf) {
                float pv[4];
#pragma unroll
                for (int i = 0; i < 4; ++i) {
                    float sv = sacc[kf][i];
                    if (msk) {
                        const int cg = k0 + kf * 16 + quad * 4 + i;
                        sv = (cg <= wrow) ? sv : -3.0e38f;
                    }
                    pv[i] = __builtin_amdgcn_exp2f(sv);
                    lpv[i] += pv[i];
                }
                Xp0[kf] = pk_bf16(pv[0], pv[1]);
                Xp1[kf] = pk_bf16(pv[2], pv[3]);
            }

            // in-register P redistribution to PV A-fragment layout (R6-verified):
            //   permlane32_swap: A=[A0,A1,B0,B1], B=[A2,A3,B2,B3]
            //   permlane16_swap: A=[A0,A2,B0,B2] (=pa dword u),
            //                    B=[A1,A3,B1,B3] (=pa dword 2+u)
            bf16x8 pa[2];
#pragma unroll
            for (int ks = 0; ks < 2; ++ks) {
                unsigned a0 = Xp0[2 * ks], b0 = Xp0[2 * ks + 1];
                asm("v_permlane32_swap_b32 %0, %1" : "+v"(a0), "+v"(b0));
                asm("v_permlane16_swap_b32 %0, %1" : "+v"(a0), "+v"(b0));
                unsigned a1 = Xp1[2 * ks], b1 = Xp1[2 * ks + 1];
                asm("v_permlane32_swap_b32 %0, %1" : "+v"(a1), "+v"(b1));
                asm("v_permlane16_swap_b32 %0, %1" : "+v"(a1), "+v"(b1));
                union { unsigned u4[4]; bf16x8 v; } P;
                P.u4[0] = a0; P.u4[1] = a1; P.u4[2] = b0; P.u4[3] = b1;
                pa[ks] = P.v;
            }

            // O += P V (pa from registers; vb from swizzled sV)
#pragma unroll
            for (int ks = 0; ks < 2; ++ks) {
                const int rgrp = (((ks * 4 + quad) ^ l8) << 3);
                bf16x8 vb[4];
#pragma unroll
                for (int nf = 0; nf < 4; ++nf)
                    vb[nf] = *(const bf16x8*)(sV + (nf * 16 + l16) * 64 + rgrp);
#pragma unroll
                for (int nf = 0; nf < 4; ++nf)
                    oacc[nf] = __builtin_amdgcn_mfma_f32_16x16x32_bf16(pa[ks], vb[nf], oacc[nf], 0, 0, 0);
            }
        }
    }

    // epilogue: reduce row-sums over quads, shuffle to C-layout rows, store
    float rs = (lpv[0] + lpv[1]) + (lpv[2] + lpv[3]);
    rs += __shfl_xor(rs, 16);
    rs += __shfl_xor(rs, 32);
#pragma unroll
    for (int i = 0; i < 4; ++i) {
        const float inv = 1.0f / __shfl(rs, quad * 4 + i);
        const int r = wbase + quad * 4 + i;
#pragma unroll
        for (int nf = 0; nf < 4; ++nf)
            y[((size_t)b * 2048 + r) * 1024 + h * 64 + nf * 16 + l16] =
                f2bf(oacc[nf][i] * inv);
    }
}

// ---------- proj GEMM: out[8192,1024] = Y[8192,1024] @ Wp[1024,1024]^T (fp32 out) ----------
// R9: retile BM=64 x BN=128 -> grid (128,8) = 1024 blocks (was 512 = 2/CU
// grid-capped). Wave tile 32x64: acc 2x4 frags = 32 AGPR; LDS 24KB.

__global__ __launch_bounds__(256, 3) void gemm_proj(
    const ushort_t* __restrict__ A, const ushort_t* __restrict__ W, float* __restrict__ out)
{
    constexpr int K = 1024;
    const int m0 = blockIdx.x * 64;
    const int n0 = blockIdx.y * 128;
    __shared__ alignas(16) ushort_t sA[4096];   // 8KB: 64 rows x 64
    __shared__ alignas(16) ushort_t sB[8192];   // 16KB: 128 rows x 64
    const int tid = threadIdx.x;
    const int wave = tid >> 6, lane = tid & 63;
    const int quad = lane >> 4, l16 = lane & 15;
    const int l8 = lane & 7;
    const int wm = (wave >> 1) << 5;            // 0 or 32
    const int wn = (wave & 1) << 6;             // 0 or 64
    const int srow8 = lane >> 3;
    const int sg = ((l8 ^ srow8) << 3);

    f32x4 acc[2][4] = {};
    // A chunks: 8 total, wave stages 2 (chunk = wave*2+c)
    // B chunks: 16 total, wave stages 4 (chunk = wave*4+c)
    const ushort_t* aRow0 = A + (size_t)(m0 + wave * 16 + srow8) * K + sg;
    const ushort_t* bRow0 = W + (size_t)(n0 + wave * 32 + srow8) * K + sg;

    for (int k0 = 0; k0 < K; k0 += 64) {
#pragma unroll
        for (int c = 0; c < 2; ++c)
            gld_lds16(aRow0 + (size_t)c * 8 * K + k0, sA + (wave * 2 + c) * 512);
#pragma unroll
        for (int c = 0; c < 4; ++c)
            gld_lds16(bRow0 + (size_t)c * 8 * K + k0, sB + (wave * 4 + c) * 512);
        __syncthreads();
#pragma unroll
        for (int ks = 0; ks < 2; ++ks) {
            const int rg = (((ks * 4 + quad) ^ l8) << 3);
            bf16x8 bfr[4];
#pragma unroll
            for (int nf = 0; nf < 4; ++nf)
                bfr[nf] = *(const bf16x8*)(sB + (wn + nf * 16 + l16) * 64 + rg);
#pragma unroll
            for (int mf = 0; mf < 2; ++mf) {
                const bf16x8 af = *(const bf16x8*)(sA + (wm + mf * 16 + l16) * 64 + rg);
#pragma unroll
                for (int nf = 0; nf < 4; ++nf)
                    acc[mf][nf] = __builtin_amdgcn_mfma_f32_16x16x32_bf16(af, bfr[nf], acc[mf][nf], 0, 0, 0);
            }
        }
        __syncthreads();
    }

#pragma unroll
    for (int mf = 0; mf < 2; ++mf)
#pragma unroll
        for (int nf = 0; nf < 4; ++nf)
#pragma unroll
            for (int i = 0; i < 4; ++i) {
                const int m = m0 + wm + mf * 16 + quad * 4 + i;
                const int n = n0 + wn + nf * 16 + l16;
                out[(size_t)m * 1024 + n] = acc[mf][nf][i];
            }
}

// ---------- launch ----------

extern "C" void kernel_launch(void* const* d_in, const int* in_sizes, int n_in,
                              void* d_out, int out_size, void* d_ws, size_t ws_size,
                              hipStream_t stream) {
    const float* x  = (const float*)d_in[0];
    const float* wa = (const float*)d_in[1];
    const float* wp = (const float*)d_in[2];
    float* out = (float*)d_out;

    char* ws = (char*)d_ws;
    // layout (bytes): xb 16MiB | wab 6MiB | wpb 2MiB | q 16MiB | k 16MiB | vt 16MiB
    ushort_t* xb  = (ushort_t*)(ws);
    ushort_t* wab = (ushort_t*)(ws + 16777216);
    ushort_t* wpb = (ushort_t*)(ws + 16777216 + 6291456);
    ushort_t* q   = (ushort_t*)(ws + 25165824);
    ushort_t* k   = (ushort_t*)(ws + 41943040);
    ushort_t* vt  = (ushort_t*)(ws + 58720256);
    ushort_t* y   = xb;   // xb dead after gemm_qkv; reuse for attention output

    convert_all<<<12288, 256, 0, stream>>>(x, wa, wp, xb, wab, wpb);

    gemm_qkv<<<dim3(64, 24), 256, 0, stream>>>(xb, wab, q, k, vt);
    attn<<<dim3(64, 16), 512, 0, stream>>>(q, k, vt, y);
    gemm_proj<<<dim3(128, 8), 256, 0, stream>>>(y, wpb, out);
}